// Round 4
// baseline (179.448 us; speedup 1.0000x reference)
//
#include <hip/hip_runtime.h>
#include <stddef.h>

#define N_NODES 10000
#define NE 320000
#define NB 32
#define SIZE1 80000
#define SIZE2 80000
#define CAP 96          // fixed CSR capacity per node; deg ~ Poisson(32), P(>96) ~ 1e-20

// d_ws layout (int offsets)
#define WS_CURSOR 0          // 10000 ints
#define WS_RECS   10000      // ulong recs[N_NODES*CAP] = 1.92M ints (byte off 40000, 8B aligned)
#define WS_XT     1930000    // bf16 xt[N_NODES][32][8] = 1.28M ints (byte 7720000, 16B aligned)

typedef short short8 __attribute__((ext_vector_type(8)));
typedef float floatx4 __attribute__((ext_vector_type(4)));
union FragU { short8 v; ushort us[8]; uint4 u4; };

__device__ inline ushort f2bf(float f) {
  union { float f; unsigned u; } c; c.f = f;
  unsigned u = c.u;
  u += 0x7fffu + ((u >> 16) & 1u);   // round-to-nearest-even
  return (ushort)(u >> 16);
}

__device__ inline unsigned pack2bf(float a, float b) {
  return (unsigned)f2bf(a) | ((unsigned)f2bf(b) << 16);
}

// Build kernel:
//  1) CSR scatter: atomicAdd cursor[row] -> one 8B record {e, col} per edge.
//  2) x fp32->bf16 transpose xt[n][b][i] with COALESCED READS: task mapping
//     b = g/10000, n = g%10000 puts consecutive lanes on consecutive n ->
//     contiguous 2KB reads per wave. The scatter moves to the write side
//     (16B @ 512B stride), which is store-buffered and L2-absorbed.
//     (r3's (n,b)=(g>>5,g&31) mapping read 64 scattered 32B segments per
//     instruction spanning 10MB — the latency-critical side was scattered.)
__global__ __launch_bounds__(256) void build_kernel(const float* __restrict__ x,
                                                    const int* __restrict__ idxs,
                                                    int* __restrict__ cursor,
                                                    unsigned long long* __restrict__ recs,
                                                    ushort* __restrict__ xt) {
  const int t = threadIdx.x;
  const int g = blockIdx.x * 256 + t;            // NE = 1250*256 exactly; NE == 32*10000
  // transpose task (issue loads first; independent of the atomic chain)
  const int b = g / 10000;                       // magic-mul
  const int n = g - b * 10000;
  const float* xp = x + (size_t)b * SIZE1 + n * 8;
  const float4 v0 = *(const float4*)xp;
  const float4 v1 = *(const float4*)(xp + 4);

  // CSR scatter
  const int r = idxs[g];
  const int c = idxs[NE + g];
  const int pos = atomicAdd(&cursor[r], 1);
  if (pos < CAP)
    recs[(size_t)r * CAP + pos] = (unsigned long long)(unsigned)g |
                                  ((unsigned long long)(unsigned)c << 32);

  // finish transpose
  FragU f;
  f.us[0] = f2bf(v0.x); f.us[1] = f2bf(v0.y); f.us[2] = f2bf(v0.z); f.us[3] = f2bf(v0.w);
  f.us[4] = f2bf(v1.x); f.us[5] = f2bf(v1.y); f.us[6] = f2bf(v1.z); f.us[7] = f2bf(v1.w);
  *(uint4*)(xt + (size_t)n * 256 + b * 8) = f.u4;
}

// ONE WAVE PER NODE (4 nodes per 256-block). No LDS, no cross-wave reduction.
// B-frag: coalesced dwordx4 vals load + in-wave shuffle transpose (r3).
// NEW: 2-deep software pipeline over the 2-slot iterations — issue iteration
// s+2's shfls+loads before computing iteration s. Explicit ping-pong stage
// regs (A/B, all statically indexed) to avoid scratch (rule #20).
struct Stage {
  float4 f0, f1;
  FragU alo0, ahi0, alo1, ahi1;
  bool ok0, ok1;
};

#define STAGE_LOAD(ST, S)                                                    \
  {                                                                          \
    const int le0 = (S) * 4 + quad;                                          \
    const int lec0 = min(le0, lim - 1);                                      \
    const int eid0 = __shfl(elo, lec0);                                      \
    const int px0  = __shfl(ehi, lec0);                                      \
    ST.ok0 = le0 < lim;                                                      \
    const int le1 = (S) * 4 + 4 + quad;                                      \
    const int lec1 = min(le1, lim - 1);                                      \
    const int eid1 = __shfl(elo, lec1);                                      \
    const int px1  = __shfl(ehi, lec1);                                      \
    ST.ok1 = le1 < lim;                                                      \
    ST.f0 = *(const float4*)(vals + (size_t)eid0 * 64 + nn * 4);             \
    ST.f1 = *(const float4*)(vals + (size_t)eid1 * 64 + nn * 4);             \
    const ushort* xr0 = xt + (size_t)px0 * 256;                              \
    const ushort* xr1 = xt + (size_t)px1 * 256;                              \
    ST.alo0.u4 = *(const uint4*)(xr0 + nn * 8);                              \
    ST.ahi0.u4 = *(const uint4*)(xr0 + 128 + nn * 8);                        \
    ST.alo1.u4 = *(const uint4*)(xr1 + nn * 8);                              \
    ST.ahi1.u4 = *(const uint4*)(xr1 + 128 + nn * 8);                        \
  }

#define STAGE_COMPUTE(ST)                                                    \
  {                                                                          \
    unsigned u00 = pack2bf(ST.f0.x, ST.f0.y), u01 = pack2bf(ST.f0.z, ST.f0.w); \
    unsigned u10 = pack2bf(ST.f1.x, ST.f1.y), u11 = pack2bf(ST.f1.z, ST.f1.w); \
    if (!ST.ok0) { u00 = 0; u01 = 0; }                                       \
    if (!ST.ok1) { u10 = 0; u11 = 0; }                                       \
    FragU b0, b1;                                                            \
    _Pragma("unroll")                                                        \
    for (int i = 0; i < 8; ++i) {                                            \
      unsigned t00 = (unsigned)__shfl((int)u00, sidx[i]);                    \
      unsigned t01 = (unsigned)__shfl((int)u01, sidx[i]);                    \
      unsigned w0 = selW ? t01 : t00;                                        \
      b0.us[i] = selH ? (ushort)(w0 >> 16) : (ushort)(w0 & 0xffffu);         \
      unsigned t10 = (unsigned)__shfl((int)u10, sidx[i]);                    \
      unsigned t11 = (unsigned)__shfl((int)u11, sidx[i]);                    \
      unsigned w1 = selW ? t11 : t10;                                        \
      b1.us[i] = selH ? (ushort)(w1 >> 16) : (ushort)(w1 & 0xffffu);         \
    }                                                                        \
    acc0 = __builtin_amdgcn_mfma_f32_16x16x32_bf16(ST.alo0.v, b0.v, acc0, 0, 0, 0); \
    acc1 = __builtin_amdgcn_mfma_f32_16x16x32_bf16(ST.ahi0.v, b0.v, acc1, 0, 0, 0); \
    acc0 = __builtin_amdgcn_mfma_f32_16x16x32_bf16(ST.alo1.v, b1.v, acc0, 0, 0, 0); \
    acc1 = __builtin_amdgcn_mfma_f32_16x16x32_bf16(ST.ahi1.v, b1.v, acc1, 0, 0, 0); \
  }

__global__ __launch_bounds__(256) void gather_mfma_kernel(const ushort* __restrict__ xt,
                                                          const float* __restrict__ vals,
                                                          const float* __restrict__ bias,
                                                          const int* __restrict__ cursor,
                                                          const unsigned long long* __restrict__ recs,
                                                          float* __restrict__ out) {
  const int t = threadIdx.x;
  const int lane = t & 63;
  const int w = t >> 6;              // wave id 0..3
  const int n = blockIdx.x * 4 + w;  // node for this wave
  const int quad = lane >> 4;
  const int nn = lane & 15;
  const int deg = min(cursor[n], CAP);
  const size_t nbase = (size_t)n * CAP;

  // Loop-invariant shuffle geometry.
  const int laneBase = lane & 48;            // quad*16
  const int p = (nn >> 2) & 1;               // which 16B half of the edge row-pair
  const bool selW = (nn & 2) != 0;           // which packed word
  const bool selH = (nn & 1) != 0;           // which half of the word
  int sidx[8];
#pragma unroll
  for (int i = 0; i < 8; ++i) sidx[i] = laneBase | (i << 1) | p;

  floatx4 acc0 = {0.f, 0.f, 0.f, 0.f};
  floatx4 acc1 = {0.f, 0.f, 0.f, 0.f};

  for (int base = 0; base < deg; base += 64) {
    const int lim = min(64, deg - base);                       // edges this chunk
    const unsigned long long rv = recs[nbase + base + min(lane, lim - 1)];  // coalesced
    const int elo = (int)(unsigned)rv;                         // edge id
    const int ehi = (int)(unsigned)(rv >> 32);                 // col (x node)
    const int nslots = (lim + 3) >> 2;                         // 4-edge slots

    Stage A, B;
    STAGE_LOAD(A, 0);
    int s = 0;
    while (true) {
      if (s + 2 < nslots) {
        STAGE_LOAD(B, s + 2);
        STAGE_COMPUTE(A);
        s += 2;
        if (s + 2 < nslots) {
          STAGE_LOAD(A, s + 2);
          STAGE_COMPUTE(B);
          s += 2;
        } else {
          STAGE_COMPUTE(B);
          break;
        }
      } else {
        STAGE_COMPUTE(A);
        break;
      }
    }
  }

  // C/D: col(j) = lane&15, row(b) = quad*4 + reg. Each wave writes its node.
  if (nn < 8) {
    const float bz = bias[n * 8 + nn];
#pragma unroll
    for (int r = 0; r < 4; ++r) {
      out[(size_t)(quad * 4 + r) * SIZE2 + n * 8 + nn] = acc0[r] + bz;
      out[(size_t)(16 + quad * 4 + r) * SIZE2 + n * 8 + nn] = acc1[r] + bz;
    }
  }
}

extern "C" void kernel_launch(void* const* d_in, const int* in_sizes, int n_in,
                              void* d_out, int out_size, void* d_ws, size_t ws_size,
                              hipStream_t stream) {
  const float* x    = (const float*)d_in[0];
  const float* vals = (const float*)d_in[1];
  const float* bias = (const float*)d_in[2];
  const int*   idxs = (const int*)d_in[3];
  float* out = (float*)d_out;

  int* ws = (int*)d_ws;
  int* cursor = ws + WS_CURSOR;
  unsigned long long* recs = (unsigned long long*)(ws + WS_RECS);
  ushort* xt = (ushort*)(ws + WS_XT);

  hipMemsetAsync(cursor, 0, N_NODES * sizeof(int), stream);

  build_kernel<<<NE / 256, 256, 0, stream>>>(x, idxs, cursor, recs, xt);
  gather_mfma_kernel<<<N_NODES / 4, 256, 0, stream>>>(xt, vals, bias, cursor, recs, out);
}

// Round 5
// 177.177 us; speedup vs baseline: 1.0128x; 1.0128x over previous
//
#include <hip/hip_runtime.h>
#include <stddef.h>

#define N_NODES 10000
#define NE 320000
#define NB 32
#define SIZE1 80000
#define SIZE2 80000
#define CAP 96          // fixed CSR capacity per node; deg ~ Poisson(32), P(>96) ~ 1e-20

// d_ws layout (int offsets)
#define WS_CURSOR 0          // 10000 ints
#define WS_RECS   10000      // ulong recs[N_NODES*CAP] = 1.92M ints (byte off 40000, 8B aligned)
#define WS_XT     1930000    // bf16 xt[N_NODES][32][8] = 1.28M ints (byte 7720000, 16B aligned)

typedef short short8 __attribute__((ext_vector_type(8)));
typedef float floatx4 __attribute__((ext_vector_type(4)));
union FragU { short8 v; ushort us[8]; uint4 u4; };

__device__ inline ushort f2bf(float f) {
  union { float f; unsigned u; } c; c.f = f;
  unsigned u = c.u;
  u += 0x7fffu + ((u >> 16) & 1u);   // round-to-nearest-even
  return (ushort)(u >> 16);
}

__device__ inline unsigned pack2bf(float a, float b) {
  return (unsigned)f2bf(a) | ((unsigned)f2bf(b) << 16);
}

// Build kernel (r4 read-coalesced variant — kept for isolation this round):
//  1) CSR scatter: atomicAdd cursor[row] -> one 8B record {e, col} per edge.
//  2) x fp32->bf16 transpose xt[n][b][i] with COALESCED READS: task mapping
//     b = g/10000, n = g%10000 -> consecutive lanes read contiguous 2KB of x;
//     the scatter moves to the store side (16B @ 512B stride, L2-absorbed).
__global__ __launch_bounds__(256) void build_kernel(const float* __restrict__ x,
                                                    const int* __restrict__ idxs,
                                                    int* __restrict__ cursor,
                                                    unsigned long long* __restrict__ recs,
                                                    ushort* __restrict__ xt) {
  const int t = threadIdx.x;
  const int g = blockIdx.x * 256 + t;            // NE = 1250*256 exactly; NE == 32*10000
  // transpose task (issue loads first; independent of the atomic chain)
  const int b = g / 10000;                       // magic-mul
  const int n = g - b * 10000;
  const float* xp = x + (size_t)b * SIZE1 + n * 8;
  const float4 v0 = *(const float4*)xp;
  const float4 v1 = *(const float4*)(xp + 4);

  // CSR scatter
  const int r = idxs[g];
  const int c = idxs[NE + g];
  const int pos = atomicAdd(&cursor[r], 1);
  if (pos < CAP)
    recs[(size_t)r * CAP + pos] = (unsigned long long)(unsigned)g |
                                  ((unsigned long long)(unsigned)c << 32);

  // finish transpose
  FragU f;
  f.us[0] = f2bf(v0.x); f.us[1] = f2bf(v0.y); f.us[2] = f2bf(v0.z); f.us[3] = f2bf(v0.w);
  f.us[4] = f2bf(v1.x); f.us[5] = f2bf(v1.y); f.us[6] = f2bf(v1.z); f.us[7] = f2bf(v1.w);
  *(uint4*)(xt + (size_t)n * 256 + b * 8) = f.u4;
}

// ONE WAVE PER NODE (4 nodes per 256-block) — r3's proven simple loop
// (2-deep software pipeline REVERTED: +48 VGPR stage cost occupancy and the
// ~4-iteration inner loop never amortized the prologue; r4 regressed +4.6us).
// B-frag: coalesced dwordx4 vals load (1KB contiguous per slot across the
// wave) + in-wave shuffle transpose to the MFMA B layout.
__global__ __launch_bounds__(256) void gather_mfma_kernel(const ushort* __restrict__ xt,
                                                          const float* __restrict__ vals,
                                                          const float* __restrict__ bias,
                                                          const int* __restrict__ cursor,
                                                          const unsigned long long* __restrict__ recs,
                                                          float* __restrict__ out) {
  const int t = threadIdx.x;
  const int lane = t & 63;
  const int w = t >> 6;              // wave id 0..3
  const int n = blockIdx.x * 4 + w;  // node for this wave
  const int quad = lane >> 4;
  const int nn = lane & 15;
  const int deg = min(cursor[n], CAP);
  const size_t nbase = (size_t)n * CAP;

  // Loop-invariant shuffle geometry.
  const int laneBase = lane & 48;            // quad*16
  const int p = (nn >> 2) & 1;               // which 16B half of the edge row-pair
  const bool selW = (nn & 2) != 0;           // which packed word
  const bool selH = (nn & 1) != 0;           // which half of the word
  int sidx[8];
#pragma unroll
  for (int i = 0; i < 8; ++i) sidx[i] = laneBase | (i << 1) | p;

  floatx4 acc0 = {0.f, 0.f, 0.f, 0.f};
  floatx4 acc1 = {0.f, 0.f, 0.f, 0.f};

  for (int base = 0; base < deg; base += 64) {
    const int lim = min(64, deg - base);                       // edges this chunk
    const unsigned long long rv = recs[nbase + base + min(lane, lim - 1)];  // coalesced
    const int elo = (int)(unsigned)rv;                         // edge id
    const int ehi = (int)(unsigned)(rv >> 32);                 // col (x node)
    const int nslots = (lim + 3) >> 2;                         // 4-edge slots

    for (int s = 0; s < nslots; s += 2) {
      // --- issue all global loads for both slots first (ILP) ---
      const int le0 = s * 4 + quad;
      const int lec0 = min(le0, lim - 1);
      const int eid0 = __shfl(elo, lec0);
      const int px0  = __shfl(ehi, lec0);
      const bool ok0 = le0 < lim;
      const int le1 = (s + 1) * 4 + quad;
      const int lec1 = min(le1, lim - 1);
      const int eid1 = __shfl(elo, lec1);
      const int px1  = __shfl(ehi, lec1);
      const bool ok1 = le1 < lim;

      float4 f0 = *(const float4*)(vals + (size_t)eid0 * 64 + nn * 4);  // coalesced 1KB/slot
      float4 f1 = *(const float4*)(vals + (size_t)eid1 * 64 + nn * 4);
      const ushort* xr0 = xt + (size_t)px0 * 256;
      const ushort* xr1 = xt + (size_t)px1 * 256;
      FragU alo0, ahi0, alo1, ahi1;
      alo0.u4 = *(const uint4*)(xr0 + nn * 8);                // batch = nn
      ahi0.u4 = *(const uint4*)(xr0 + 128 + nn * 8);          // batch = nn+16
      alo1.u4 = *(const uint4*)(xr1 + nn * 8);
      ahi1.u4 = *(const uint4*)(xr1 + 128 + nn * 8);

      // --- convert + zero invalid edges (keeps B exactly 0) ---
      unsigned u00 = pack2bf(f0.x, f0.y), u01 = pack2bf(f0.z, f0.w);
      unsigned u10 = pack2bf(f1.x, f1.y), u11 = pack2bf(f1.z, f1.w);
      if (!ok0) { u00 = 0; u01 = 0; }
      if (!ok1) { u10 = 0; u11 = 0; }

      // --- in-wave transpose to B layout: lane nn <- column j=nn ---
      FragU b0, b1;
#pragma unroll
      for (int i = 0; i < 8; ++i) {
        unsigned t00 = (unsigned)__shfl((int)u00, sidx[i]);
        unsigned t01 = (unsigned)__shfl((int)u01, sidx[i]);
        unsigned w0 = selW ? t01 : t00;
        b0.us[i] = selH ? (ushort)(w0 >> 16) : (ushort)(w0 & 0xffffu);
        unsigned t10 = (unsigned)__shfl((int)u10, sidx[i]);
        unsigned t11 = (unsigned)__shfl((int)u11, sidx[i]);
        unsigned w1 = selW ? t11 : t10;
        b1.us[i] = selH ? (ushort)(w1 >> 16) : (ushort)(w1 & 0xffffu);
      }

      acc0 = __builtin_amdgcn_mfma_f32_16x16x32_bf16(alo0.v, b0.v, acc0, 0, 0, 0);
      acc1 = __builtin_amdgcn_mfma_f32_16x16x32_bf16(ahi0.v, b0.v, acc1, 0, 0, 0);
      acc0 = __builtin_amdgcn_mfma_f32_16x16x32_bf16(alo1.v, b1.v, acc0, 0, 0, 0);
      acc1 = __builtin_amdgcn_mfma_f32_16x16x32_bf16(ahi1.v, b1.v, acc1, 0, 0, 0);
    }
  }

  // C/D: col(j) = lane&15, row(b) = quad*4 + reg. Each wave writes its node.
  if (nn < 8) {
    const float bz = bias[n * 8 + nn];
#pragma unroll
    for (int r = 0; r < 4; ++r) {
      out[(size_t)(quad * 4 + r) * SIZE2 + n * 8 + nn] = acc0[r] + bz;
      out[(size_t)(16 + quad * 4 + r) * SIZE2 + n * 8 + nn] = acc1[r] + bz;
    }
  }
}

extern "C" void kernel_launch(void* const* d_in, const int* in_sizes, int n_in,
                              void* d_out, int out_size, void* d_ws, size_t ws_size,
                              hipStream_t stream) {
  const float* x    = (const float*)d_in[0];
  const float* vals = (const float*)d_in[1];
  const float* bias = (const float*)d_in[2];
  const int*   idxs = (const int*)d_in[3];
  float* out = (float*)d_out;

  int* ws = (int*)d_ws;
  int* cursor = ws + WS_CURSOR;
  unsigned long long* recs = (unsigned long long*)(ws + WS_RECS);
  ushort* xt = (ushort*)(ws + WS_XT);

  hipMemsetAsync(cursor, 0, N_NODES * sizeof(int), stream);

  build_kernel<<<NE / 256, 256, 0, stream>>>(x, idxs, cursor, recs, xt);
  gather_mfma_kernel<<<N_NODES / 4, 256, 0, stream>>>(xt, vals, bias, cursor, recs, out);
}

// Round 6
// 165.764 us; speedup vs baseline: 1.0826x; 1.0689x over previous
//
#include <hip/hip_runtime.h>
#include <stddef.h>

#define N_NODES 10000
#define NE 320000
#define NB 32
#define SIZE1 80000
#define SIZE2 80000
#define CAP 96          // fixed CSR capacity per node; deg ~ Poisson(32), P(>96) ~ 1e-20
#define CSTRIDE 32      // cursor padding: 1 counter per 128B L2 line (atomic RMW
                        // serializes per line; 32 counters/line = 32-way false serialization)

// d_ws layout (int offsets)
#define WS_CURSOR 0          // int[N_NODES*CSTRIDE] = 320000 ints (1.28 MB, padded)
#define WS_RECS   320000     // ulong recs[N_NODES*CAP] = 1.92M ints (byte 1280000, 8B aligned)
#define WS_XT     2240000    // bf16 xt[N_NODES][32][8] = 1.28M ints (byte 8960000, 16B aligned)

typedef short short8 __attribute__((ext_vector_type(8)));
typedef float floatx4 __attribute__((ext_vector_type(4)));
union FragU { short8 v; ushort us[8]; uint4 u4; };

__device__ inline ushort f2bf(float f) {
  union { float f; unsigned u; } c; c.f = f;
  unsigned u = c.u;
  u += 0x7fffu + ((u >> 16) & 1u);   // round-to-nearest-even
  return (ushort)(u >> 16);
}

__device__ inline unsigned pack2bf(float a, float b) {
  return (unsigned)f2bf(a) | ((unsigned)f2bf(b) << 16);
}

// Build kernel (v1 mapping — proven best in r3; r5 showed read-coalescing is
// not the lever, so the transpose side is restored and ONLY the cursor
// padding changes this round):
//  1) CSR scatter: atomicAdd cursor[row*CSTRIDE] -> one 8B record {e, col}.
//  2) x fp32->bf16 transpose xt[n][b][i], LDS-free, (n,b) = (g>>5, g&31):
//     scattered 32B reads, contiguous 512B writes.
__global__ __launch_bounds__(256) void build_kernel(const float* __restrict__ x,
                                                    const int* __restrict__ idxs,
                                                    int* __restrict__ cursor,
                                                    unsigned long long* __restrict__ recs,
                                                    ushort* __restrict__ xt) {
  const int t = threadIdx.x;
  const int g = blockIdx.x * 256 + t;            // NE = 1250*256 exactly
  // transpose task loads first (independent of the atomic chain)
  const int n = g >> 5;
  const int b = g & 31;
  const float* xp = x + (size_t)b * SIZE1 + n * 8;
  const float4 v0 = *(const float4*)xp;
  const float4 v1 = *(const float4*)(xp + 4);

  // CSR scatter (padded cursor: 1 counter per 128B line)
  const int r = idxs[g];
  const int c = idxs[NE + g];
  const int pos = atomicAdd(&cursor[r * CSTRIDE], 1);
  if (pos < CAP)
    recs[(size_t)r * CAP + pos] = (unsigned long long)(unsigned)g |
                                  ((unsigned long long)(unsigned)c << 32);

  // finish transpose
  FragU f;
  f.us[0] = f2bf(v0.x); f.us[1] = f2bf(v0.y); f.us[2] = f2bf(v0.z); f.us[3] = f2bf(v0.w);
  f.us[4] = f2bf(v1.x); f.us[5] = f2bf(v1.y); f.us[6] = f2bf(v1.z); f.us[7] = f2bf(v1.w);
  *(uint4*)(xt + (size_t)n * 256 + b * 8) = f.u4;
}

// ONE WAVE PER NODE (4 nodes per 256-block) — r3's proven simple loop.
// B-frag: coalesced dwordx4 vals load (1KB contiguous per slot across the
// wave) + in-wave shuffle transpose to the MFMA B layout.
__global__ __launch_bounds__(256) void gather_mfma_kernel(const ushort* __restrict__ xt,
                                                          const float* __restrict__ vals,
                                                          const float* __restrict__ bias,
                                                          const int* __restrict__ cursor,
                                                          const unsigned long long* __restrict__ recs,
                                                          float* __restrict__ out) {
  const int t = threadIdx.x;
  const int lane = t & 63;
  const int w = t >> 6;              // wave id 0..3
  const int n = blockIdx.x * 4 + w;  // node for this wave
  const int quad = lane >> 4;
  const int nn = lane & 15;
  const int deg = min(cursor[n * CSTRIDE], CAP);
  const size_t nbase = (size_t)n * CAP;

  // Loop-invariant shuffle geometry.
  const int laneBase = lane & 48;            // quad*16
  const int p = (nn >> 2) & 1;               // which 16B half of the edge row-pair
  const bool selW = (nn & 2) != 0;           // which packed word
  const bool selH = (nn & 1) != 0;           // which half of the word
  int sidx[8];
#pragma unroll
  for (int i = 0; i < 8; ++i) sidx[i] = laneBase | (i << 1) | p;

  floatx4 acc0 = {0.f, 0.f, 0.f, 0.f};
  floatx4 acc1 = {0.f, 0.f, 0.f, 0.f};

  for (int base = 0; base < deg; base += 64) {
    const int lim = min(64, deg - base);                       // edges this chunk
    const unsigned long long rv = recs[nbase + base + min(lane, lim - 1)];  // coalesced
    const int elo = (int)(unsigned)rv;                         // edge id
    const int ehi = (int)(unsigned)(rv >> 32);                 // col (x node)
    const int nslots = (lim + 3) >> 2;                         // 4-edge slots

    for (int s = 0; s < nslots; s += 2) {
      // --- issue all global loads for both slots first (ILP) ---
      const int le0 = s * 4 + quad;
      const int lec0 = min(le0, lim - 1);
      const int eid0 = __shfl(elo, lec0);
      const int px0  = __shfl(ehi, lec0);
      const bool ok0 = le0 < lim;
      const int le1 = (s + 1) * 4 + quad;
      const int lec1 = min(le1, lim - 1);
      const int eid1 = __shfl(elo, lec1);
      const int px1  = __shfl(ehi, lec1);
      const bool ok1 = le1 < lim;

      float4 f0 = *(const float4*)(vals + (size_t)eid0 * 64 + nn * 4);  // coalesced 1KB/slot
      float4 f1 = *(const float4*)(vals + (size_t)eid1 * 64 + nn * 4);
      const ushort* xr0 = xt + (size_t)px0 * 256;
      const ushort* xr1 = xt + (size_t)px1 * 256;
      FragU alo0, ahi0, alo1, ahi1;
      alo0.u4 = *(const uint4*)(xr0 + nn * 8);                // batch = nn
      ahi0.u4 = *(const uint4*)(xr0 + 128 + nn * 8);          // batch = nn+16
      alo1.u4 = *(const uint4*)(xr1 + nn * 8);
      ahi1.u4 = *(const uint4*)(xr1 + 128 + nn * 8);

      // --- convert + zero invalid edges (keeps B exactly 0) ---
      unsigned u00 = pack2bf(f0.x, f0.y), u01 = pack2bf(f0.z, f0.w);
      unsigned u10 = pack2bf(f1.x, f1.y), u11 = pack2bf(f1.z, f1.w);
      if (!ok0) { u00 = 0; u01 = 0; }
      if (!ok1) { u10 = 0; u11 = 0; }

      // --- in-wave transpose to B layout: lane nn <- column j=nn ---
      FragU b0, b1;
#pragma unroll
      for (int i = 0; i < 8; ++i) {
        unsigned t00 = (unsigned)__shfl((int)u00, sidx[i]);
        unsigned t01 = (unsigned)__shfl((int)u01, sidx[i]);
        unsigned w0 = selW ? t01 : t00;
        b0.us[i] = selH ? (ushort)(w0 >> 16) : (ushort)(w0 & 0xffffu);
        unsigned t10 = (unsigned)__shfl((int)u10, sidx[i]);
        unsigned t11 = (unsigned)__shfl((int)u11, sidx[i]);
        unsigned w1 = selW ? t11 : t10;
        b1.us[i] = selH ? (ushort)(w1 >> 16) : (ushort)(w1 & 0xffffu);
      }

      acc0 = __builtin_amdgcn_mfma_f32_16x16x32_bf16(alo0.v, b0.v, acc0, 0, 0, 0);
      acc1 = __builtin_amdgcn_mfma_f32_16x16x32_bf16(ahi0.v, b0.v, acc1, 0, 0, 0);
      acc0 = __builtin_amdgcn_mfma_f32_16x16x32_bf16(alo1.v, b1.v, acc0, 0, 0, 0);
      acc1 = __builtin_amdgcn_mfma_f32_16x16x32_bf16(ahi1.v, b1.v, acc1, 0, 0, 0);
    }
  }

  // C/D: col(j) = lane&15, row(b) = quad*4 + reg. Each wave writes its node.
  if (nn < 8) {
    const float bz = bias[n * 8 + nn];
#pragma unroll
    for (int r = 0; r < 4; ++r) {
      out[(size_t)(quad * 4 + r) * SIZE2 + n * 8 + nn] = acc0[r] + bz;
      out[(size_t)(16 + quad * 4 + r) * SIZE2 + n * 8 + nn] = acc1[r] + bz;
    }
  }
}

extern "C" void kernel_launch(void* const* d_in, const int* in_sizes, int n_in,
                              void* d_out, int out_size, void* d_ws, size_t ws_size,
                              hipStream_t stream) {
  const float* x    = (const float*)d_in[0];
  const float* vals = (const float*)d_in[1];
  const float* bias = (const float*)d_in[2];
  const int*   idxs = (const int*)d_in[3];
  float* out = (float*)d_out;

  int* ws = (int*)d_ws;
  int* cursor = ws + WS_CURSOR;
  unsigned long long* recs = (unsigned long long*)(ws + WS_RECS);
  ushort* xt = (ushort*)(ws + WS_XT);

  hipMemsetAsync(cursor, 0, N_NODES * CSTRIDE * sizeof(int), stream);

  build_kernel<<<NE / 256, 256, 0, stream>>>(x, idxs, cursor, recs, xt);
  gather_mfma_kernel<<<N_NODES / 4, 256, 0, stream>>>(xt, vals, bias, cursor, recs, out);
}